// Round 4
// baseline (458.681 us; speedup 1.0000x reference)
//
#include <hip/hip_runtime.h>
#include <math.h>

#define Bb 64
#define Ll 1024
#define Dd 512
#define Aa 512
#define NEG_INF -1e9f

#define LOG2E  1.4426950408889634f
#define LOG2E2 2.8853901617526703f   // 2*log2(e)
#define NCH 64                       // l-chunks per row (16 l each)

typedef float fx4 __attribute__((ext_vector_type(4)));

__device__ __forceinline__ float fast_exp2(float x) { return __builtin_amdgcn_exp2f(x); }
__device__ __forceinline__ float fast_rcp(float x)  { return __builtin_amdgcn_rcpf(x); }

// K1: qb[b][a] = dot(decoder_h[b,:], W[a,:]) + bias[a]
//     vv2[a] = 2*g*v[a]/||v||; scal[0] = sum_a vv[a] + vbias + r  (b==0 only)
//     also zeroes the K2 handshake counters (kernel-boundary ordering => race-free)
__global__ __launch_bounds__(512) void k_qb(const float* __restrict__ dh,
                                            const float* __restrict__ W,
                                            const float* __restrict__ bias,
                                            const float* __restrict__ vw,
                                            const float* __restrict__ vg,
                                            const float* __restrict__ vb,
                                            const float* __restrict__ r,
                                            float* __restrict__ qb,
                                            float* __restrict__ vv2,
                                            float* __restrict__ scal,
                                            unsigned* __restrict__ cnt) {
    __shared__ float h[Dd];
    __shared__ float red[8];
    const int b = blockIdx.x;
    const int a = threadIdx.x;
    if (a < NCH) cnt[b * NCH + a] = 0u;   // 64 blocks x 64 = all 4096 counters
    h[a] = dh[b * Dd + a];

    float w = vw[a];
    float s = w * w;
    #pragma unroll
    for (int off = 32; off; off >>= 1) s += __shfl_xor(s, off);
    const int wave = a >> 6, lane = a & 63;
    if (lane == 0) red[wave] = s;
    __syncthreads();
    float tot = red[0] + red[1] + red[2] + red[3] + red[4] + red[5] + red[6] + red[7];
    float inv = rsqrtf(tot);
    float vva = vg[0] * w * inv;

    float acc = 0.f;
    const float4* Wr = (const float4*)(W + (size_t)a * Dd);
    #pragma unroll 8
    for (int d4 = 0; d4 < Dd / 4; ++d4) {
        float4 wq = Wr[d4];
        int d = d4 * 4;
        acc = fmaf(wq.x, h[d + 0], acc);
        acc = fmaf(wq.y, h[d + 1], acc);
        acc = fmaf(wq.z, h[d + 2], acc);
        acc = fmaf(wq.w, h[d + 3], acc);
    }
    qb[b * Aa + a] = acc + bias[a];

    if (b == 0) {
        vv2[a] = 2.f * vva;
        float s2 = vva;
        #pragma unroll
        for (int off = 32; off; off >>= 1) s2 += __shfl_xor(s2, off);
        __syncthreads();
        if (lane == 0) red[wave] = s2;
        __syncthreads();
        if (a == 0) {
            float sv = red[0] + red[1] + red[2] + red[3] + red[4] + red[5] + red[6] + red[7];
            scal[0] = sv + vb[0] + r[0];
        }
    }
}

// K2: energy+sigmoid for 16 l per block; c==0 block of each row aggregates the
// row scan once all 64 chunks have published (producers never spin -> no deadlock).
__global__ __launch_bounds__(256) void k_energy_scan(const float* __restrict__ key,
                                                     const float* __restrict__ noise,
                                                     const float* __restrict__ mask,
                                                     const float* __restrict__ qb,
                                                     const float* __restrict__ vv2,
                                                     const float* __restrict__ scal,
                                                     const float* __restrict__ prev,
                                                     float* __restrict__ p,
                                                     unsigned* __restrict__ cnt,
                                                     float* __restrict__ alpha) {
    const int b = blockIdx.y;
    const int c = blockIdx.x;
    const int l0 = c * 16;
    const int tid = threadIdx.x;
    const int wave = tid >> 6, lane = tid & 63;

    const float4* qb4 = (const float4*)(qb + (size_t)b * Aa);
    float4 q0 = qb4[lane];
    float4 q1 = qb4[lane + 64];
    const float4* v4 = (const float4*)vv2;
    const float4 v0 = v4[lane];
    const float4 v1 = v4[lane + 64];
    const float ec = scal[0];

    q0.x *= LOG2E2; q0.y *= LOG2E2; q0.z *= LOG2E2; q0.w *= LOG2E2;
    q1.x *= LOG2E2; q1.y *= LOG2E2; q1.z *= LOG2E2; q1.w *= LOG2E2;

    #pragma unroll
    for (int il = 0; il < 4; ++il) {
        const int l = l0 + wave * 4 + il;
        const fx4* kp = (const fx4*)(key + ((size_t)b * Ll + l) * Aa);
        fx4 ka = __builtin_nontemporal_load(kp + lane);
        fx4 kb = __builtin_nontemporal_load(kp + lane + 64);

        float acc = 0.f;
        acc = fmaf(v0.x, fast_rcp(fast_exp2(fmaf(ka.x, LOG2E2, q0.x)) + 1.f), acc);
        acc = fmaf(v0.y, fast_rcp(fast_exp2(fmaf(ka.y, LOG2E2, q0.y)) + 1.f), acc);
        acc = fmaf(v0.z, fast_rcp(fast_exp2(fmaf(ka.z, LOG2E2, q0.z)) + 1.f), acc);
        acc = fmaf(v0.w, fast_rcp(fast_exp2(fmaf(ka.w, LOG2E2, q0.w)) + 1.f), acc);
        acc = fmaf(v1.x, fast_rcp(fast_exp2(fmaf(kb.x, LOG2E2, q1.x)) + 1.f), acc);
        acc = fmaf(v1.y, fast_rcp(fast_exp2(fmaf(kb.y, LOG2E2, q1.y)) + 1.f), acc);
        acc = fmaf(v1.z, fast_rcp(fast_exp2(fmaf(kb.z, LOG2E2, q1.z)) + 1.f), acc);
        acc = fmaf(v1.w, fast_rcp(fast_exp2(fmaf(kb.w, LOG2E2, q1.w)) + 1.f), acc);

        #pragma unroll
        for (int off = 32; off; off >>= 1) acc += __shfl_xor(acc, off);

        if (lane == 0) {
            const float m = mask[b * Ll + l];
            float e = (m > 0.f) ? (ec - acc) : NEG_INF;
            float z = e + noise[b * Ll + l];
            float pv = fast_rcp(1.f + fast_exp2(-z * LOG2E));
            float mn = (l == Ll - 1) ? 0.f : mask[b * Ll + l + 1];
            float em = m * (1.f - mn);
            if (em > 0.f) pv = em;
            p[b * Ll + l] = pv;
        }
    }

    __syncthreads();
    if (tid == 0) {
        __threadfence();                                   // publish p stores (agent scope)
        atomicAdd(&cnt[b * NCH + c], 1u);                  // device-scope by default
    }
    if (c != 0) return;

    // ---- aggregator: whole-row scan (256 threads, 4 elems each) ----
    if (tid == 0) {
        for (int cc = 1; cc < NCH; ++cc)
            while (__hip_atomic_load(&cnt[b * NCH + cc], __ATOMIC_ACQUIRE,
                                     __HIP_MEMORY_SCOPE_AGENT) == 0u)
                __builtin_amdgcn_s_sleep(4);
        __threadfence();
    }
    __syncthreads();

    __shared__ float wA[4], wB[4];
    const float* prow = p + (size_t)b * Ll;
    const float4 pp = ((const float4*)prow)[tid];
    const float4 pa = ((const float4*)(prev + (size_t)b * Ll))[tid];
    float pm1 = 0.f;
    if (tid) pm1 = prow[tid * 4 - 1];
    const float a0 = 1.f - pm1;
    const float a1 = 1.f - pp.x;
    const float a2 = 1.f - pp.y;
    const float a3 = 1.f - pp.z;

    // local affine transform over 4 elements: x_out = A*x_in + Bv
    float A = a0, Bv = pa.x;
    Bv = fmaf(a1, Bv, pa.y); A *= a1;
    Bv = fmaf(a2, Bv, pa.z); A *= a2;
    Bv = fmaf(a3, Bv, pa.w); A *= a3;

    // wave-level inclusive scan over thread transforms
    float Ai = A, Bi = Bv;
    #pragma unroll
    for (int off = 1; off < 64; off <<= 1) {
        float qA = __shfl_up(Ai, off);
        float qB = __shfl_up(Bi, off);
        if (lane >= off) { Bi = fmaf(Ai, qB, Bi); Ai *= qA; }
    }
    float eA = __shfl_up(Ai, 1), eB = __shfl_up(Bi, 1);
    if (lane == 0) { eA = 1.f; eB = 0.f; }
    if (lane == 63) { wA[wave] = Ai; wB[wave] = Bi; }
    __syncthreads();
    float bwe = 0.f;                        // x entering this wave (x_{-1}=0)
    for (int w2 = 0; w2 < wave; ++w2) bwe = fmaf(wA[w2], bwe, wB[w2]);
    float x = fmaf(eA, bwe, eB);            // x entering this thread

    float4 o;
    x = fmaf(a0, x, pa.x); o.x = pp.x * x;
    x = fmaf(a1, x, pa.y); o.y = pp.y * x;
    x = fmaf(a2, x, pa.z); o.z = pp.z * x;
    x = fmaf(a3, x, pa.w); o.w = pp.w * x;
    ((float4*)(alpha + (size_t)b * Ll))[tid] = o;
}

extern "C" void kernel_launch(void* const* d_in, const int* in_sizes, int n_in,
                              void* d_out, int out_size, void* d_ws, size_t ws_size,
                              hipStream_t stream) {
    const float* dh    = (const float*)d_in[0];   // decoder_h [B,D]
    const float* key   = (const float*)d_in[1];   // key [B,L,A]
    // d_in[2] encoder_outputs — unused by the reference
    const float* prev  = (const float*)d_in[3];   // prev_att [B,L]
    const float* noise = (const float*)d_in[4];   // noise [B,L]
    const float* mask  = (const float*)d_in[5];   // mask [B,L]
    const float* W     = (const float*)d_in[6];   // W [A,D]
    const float* bias  = (const float*)d_in[7];   // b [A]
    const float* vw    = (const float*)d_in[8];   // v_weight [1,A]
    const float* vg    = (const float*)d_in[9];   // v_g [1]
    const float* vb    = (const float*)d_in[10];  // v_bias [1]
    const float* r     = (const float*)d_in[11];  // r [1]
    float* out = (float*)d_out;

    float* ws      = (float*)d_ws;
    float* vv2     = ws;                          // 512 floats
    float* scal    = ws + Aa;                     // 1 float (padded to 1024)
    float* qb      = ws + 1024;                   // 64*512
    float* p       = ws + 1024 + Bb * Aa;         // 64*1024
    unsigned* cnt  = (unsigned*)(ws + 1024 + Bb * Aa + Bb * Ll);  // 4096 u32

    k_qb<<<Bb, 512, 0, stream>>>(dh, W, bias, vw, vg, vb, r, qb, vv2, scal, cnt);
    k_energy_scan<<<dim3(NCH, Bb), 256, 0, stream>>>(key, noise, mask, qb, vv2, scal,
                                                     prev, p, cnt, out);
}

// Round 5
// 38.777 us; speedup vs baseline: 11.8286x; 11.8286x over previous
//
#include <hip/hip_runtime.h>
#include <math.h>

#define Bb 64
#define Ll 1024
#define Dd 512
#define Aa 512
#define NEG_INF -1e9f

#define LOG2E  1.4426950408889634f
#define LOG2E2 2.8853901617526703f   // 2*log2(e)

typedef float fx4 __attribute__((ext_vector_type(4)));

__device__ __forceinline__ float fast_exp2(float x) { return __builtin_amdgcn_exp2f(x); }
__device__ __forceinline__ float fast_rcp(float x)  { return __builtin_amdgcn_rcpf(x); }

// ---------------- K1: qb = dh @ W^T + bias;  vv2, scal ----------------
// grid (4, 64), 256 threads. Thread = half of one W row. Block (0,0) also
// computes vv2[a] = 2*g*v[a]/||v|| and scal[0] = sum_a g*v[a]/||v|| + vb + r.
__global__ __launch_bounds__(256) void k_qb(const float* __restrict__ dh,
                                            const float* __restrict__ W,
                                            const float* __restrict__ bias,
                                            const float* __restrict__ vw,
                                            const float* __restrict__ vg,
                                            const float* __restrict__ vb,
                                            const float* __restrict__ r,
                                            float* __restrict__ qb,
                                            float* __restrict__ vv2,
                                            float* __restrict__ scal) {
    __shared__ float h[Dd];
    __shared__ float red[4];
    const int b = blockIdx.y;
    const int c = blockIdx.x;            // a-chunk of 128
    const int tid = threadIdx.x;
    const int a = c * 128 + (tid >> 1);
    const int half = tid & 1;

    ((float2*)h)[tid] = ((const float2*)(dh + (size_t)b * Dd))[tid];
    __syncthreads();

    const float4* Wr = (const float4*)(W + (size_t)a * Dd + half * 256);
    const float4* h4 = (const float4*)(h + half * 256);
    float acc = 0.f;
    #pragma unroll 8
    for (int i = 0; i < 64; ++i) {
        float4 wq = Wr[i];
        float4 hv = h4[i];
        acc = fmaf(wq.x, hv.x, acc);
        acc = fmaf(wq.y, hv.y, acc);
        acc = fmaf(wq.z, hv.z, acc);
        acc = fmaf(wq.w, hv.w, acc);
    }
    acc += __shfl_xor(acc, 1);
    if (half == 0) qb[(size_t)b * Aa + a] = acc + bias[a];

    if (b == 0 && c == 0) {
        const int wave = tid >> 6, lane = tid & 63;
        float w0 = vw[tid], w1 = vw[tid + 256];
        float s = fmaf(w0, w0, w1 * w1);
        #pragma unroll
        for (int off = 32; off; off >>= 1) s += __shfl_xor(s, off);
        if (lane == 0) red[wave] = s;
        __syncthreads();
        float tot = red[0] + red[1] + red[2] + red[3];
        float inv = rsqrtf(tot);
        float g = vg[0];
        float vva0 = g * w0 * inv, vva1 = g * w1 * inv;
        vv2[tid] = 2.f * vva0;
        vv2[tid + 256] = 2.f * vva1;
        float s2 = vva0 + vva1;
        #pragma unroll
        for (int off = 32; off; off >>= 1) s2 += __shfl_xor(s2, off);
        __syncthreads();
        if (lane == 0) red[wave] = s2;
        __syncthreads();
        if (tid == 0)
            scal[0] = red[0] + red[1] + red[2] + red[3] + vb[0] + r[0];
    }
}

// ---------------- K2: p = masked sigmoid(energy + noise) ----------------
// grid (32, 64), 256 threads. One wave owns 8 consecutive l rows; all 16
// key loads issued up-front (sched_barrier pins them) for high MLP.
#define TERMS(ACC, KA, KB, Q0, Q1, V0, V1)                                      \
    ACC = fmaf(V0.x, fast_rcp(fast_exp2(fmaf(KA.x, LOG2E2, Q0.x)) + 1.f), ACC); \
    ACC = fmaf(V0.y, fast_rcp(fast_exp2(fmaf(KA.y, LOG2E2, Q0.y)) + 1.f), ACC); \
    ACC = fmaf(V0.z, fast_rcp(fast_exp2(fmaf(KA.z, LOG2E2, Q0.z)) + 1.f), ACC); \
    ACC = fmaf(V0.w, fast_rcp(fast_exp2(fmaf(KA.w, LOG2E2, Q0.w)) + 1.f), ACC); \
    ACC = fmaf(V1.x, fast_rcp(fast_exp2(fmaf(KB.x, LOG2E2, Q1.x)) + 1.f), ACC); \
    ACC = fmaf(V1.y, fast_rcp(fast_exp2(fmaf(KB.y, LOG2E2, Q1.y)) + 1.f), ACC); \
    ACC = fmaf(V1.z, fast_rcp(fast_exp2(fmaf(KB.z, LOG2E2, Q1.z)) + 1.f), ACC); \
    ACC = fmaf(V1.w, fast_rcp(fast_exp2(fmaf(KB.w, LOG2E2, Q1.w)) + 1.f), ACC);

#define RED6(A)                    \
    A += __shfl_xor(A, 32);        \
    A += __shfl_xor(A, 16);        \
    A += __shfl_xor(A, 8);         \
    A += __shfl_xor(A, 4);         \
    A += __shfl_xor(A, 2);         \
    A += __shfl_xor(A, 1);

__global__ __launch_bounds__(256) void k_energy(const float* __restrict__ key,
                                                const float* __restrict__ noise,
                                                const float* __restrict__ mask,
                                                const float* __restrict__ qb,
                                                const float* __restrict__ vv2,
                                                const float* __restrict__ scal,
                                                float* __restrict__ p) {
    const int b = blockIdx.y;
    const int tid = threadIdx.x;
    const int wave = tid >> 6, lane = tid & 63;
    const int lw0 = blockIdx.x * 32 + wave * 8;      // this wave's first l

    const fx4* qb4 = (const fx4*)(qb + (size_t)b * Aa);
    fx4 q0 = qb4[lane];
    fx4 q1 = qb4[lane + 64];
    const fx4* v4 = (const fx4*)vv2;
    const fx4 v0 = v4[lane];
    const fx4 v1 = v4[lane + 64];
    const float ec = scal[0];
    q0 *= LOG2E2;
    q1 *= LOG2E2;

    // epilogue operands: lane j (mod 8) mirrors row lw0+j
    const int lj = lane & 7;
    const int l = lw0 + lj;
    const float mk = mask[(size_t)b * Ll + l];
    const float nz = noise[(size_t)b * Ll + l];
    const float mn = (l == Ll - 1) ? 0.f : mask[(size_t)b * Ll + l + 1];

    // 16 key loads, all in flight
    const fx4* kp = (const fx4*)(key + ((size_t)b * Ll + lw0) * Aa);  // row = 128 fx4
    fx4 ka0 = kp[lane];           fx4 kb0 = kp[lane + 64];
    fx4 ka1 = kp[lane + 128];     fx4 kb1 = kp[lane + 192];
    fx4 ka2 = kp[lane + 256];     fx4 kb2 = kp[lane + 320];
    fx4 ka3 = kp[lane + 384];     fx4 kb3 = kp[lane + 448];
    fx4 ka4 = kp[lane + 512];     fx4 kb4 = kp[lane + 576];
    fx4 ka5 = kp[lane + 640];     fx4 kb5 = kp[lane + 704];
    fx4 ka6 = kp[lane + 768];     fx4 kb6 = kp[lane + 832];
    fx4 ka7 = kp[lane + 896];     fx4 kb7 = kp[lane + 960];
    __builtin_amdgcn_sched_barrier(0);   // keep all loads above the compute

    float a0 = 0.f, a1 = 0.f, a2 = 0.f, a3 = 0.f, a4 = 0.f, a5 = 0.f, a6 = 0.f, a7 = 0.f;
    TERMS(a0, ka0, kb0, q0, q1, v0, v1)
    TERMS(a1, ka1, kb1, q0, q1, v0, v1)
    TERMS(a2, ka2, kb2, q0, q1, v0, v1)
    TERMS(a3, ka3, kb3, q0, q1, v0, v1)
    TERMS(a4, ka4, kb4, q0, q1, v0, v1)
    TERMS(a5, ka5, kb5, q0, q1, v0, v1)
    TERMS(a6, ka6, kb6, q0, q1, v0, v1)
    TERMS(a7, ka7, kb7, q0, q1, v0, v1)

    RED6(a0) RED6(a1) RED6(a2) RED6(a3) RED6(a4) RED6(a5) RED6(a6) RED6(a7)

    float sel = a0;
    sel = (lj == 1) ? a1 : sel;
    sel = (lj == 2) ? a2 : sel;
    sel = (lj == 3) ? a3 : sel;
    sel = (lj == 4) ? a4 : sel;
    sel = (lj == 5) ? a5 : sel;
    sel = (lj == 6) ? a6 : sel;
    sel = (lj == 7) ? a7 : sel;

    float e = (mk > 0.f) ? (ec - sel) : NEG_INF;
    float z = e + nz;
    float pv = fast_rcp(1.f + fast_exp2(-z * LOG2E));
    float em = mk * (1.f - mn);
    if (em > 0.f) pv = em;
    if (lane < 8) p[(size_t)b * Ll + l] = pv;
}

// ---------------- K3: alpha = p * linear_recurrence ----------------
__global__ __launch_bounds__(64) void k_scan(const float* __restrict__ p,
                                             const float* __restrict__ prev,
                                             float* __restrict__ alpha) {
    const int b = blockIdx.x;
    const int lane = threadIdx.x;
    const float4* p4 = (const float4*)(p + (size_t)b * Ll);
    const float4* a4 = (const float4*)(prev + (size_t)b * Ll);

    float pr[16], pa[16];
    #pragma unroll
    for (int k = 0; k < 4; ++k) {
        float4 t = p4[lane * 4 + k];
        pr[k * 4 + 0] = t.x; pr[k * 4 + 1] = t.y; pr[k * 4 + 2] = t.z; pr[k * 4 + 3] = t.w;
        float4 u = a4[lane * 4 + k];
        pa[k * 4 + 0] = u.x; pa[k * 4 + 1] = u.y; pa[k * 4 + 2] = u.z; pa[k * 4 + 3] = u.w;
    }
    float pm1 = __shfl_up(pr[15], 1);
    if (lane == 0) pm1 = 0.f;

    float Ax = 1.f, Bx = 0.f;
    #pragma unroll
    for (int k = 0; k < 16; ++k) {
        float aj = 1.f - ((k == 0) ? pm1 : pr[k - 1]);
        Bx = fmaf(aj, Bx, pa[k]);
        Ax *= aj;
    }
    #pragma unroll
    for (int off = 1; off < 64; off <<= 1) {
        float pA = __shfl_up(Ax, off);
        float pB = __shfl_up(Bx, off);
        if (lane >= off) { Bx = fmaf(Ax, pB, Bx); Ax *= pA; }
    }
    float xin = __shfl_up(Bx, 1);
    if (lane == 0) xin = 0.f;

    float x = xin;
    float out[16];
    #pragma unroll
    for (int k = 0; k < 16; ++k) {
        float aj = 1.f - ((k == 0) ? pm1 : pr[k - 1]);
        x = fmaf(aj, x, pa[k]);
        out[k] = pr[k] * x;
    }
    float4* o4 = (float4*)(alpha + (size_t)b * Ll);
    #pragma unroll
    for (int k = 0; k < 4; ++k) {
        float4 t;
        t.x = out[k * 4 + 0]; t.y = out[k * 4 + 1]; t.z = out[k * 4 + 2]; t.w = out[k * 4 + 3];
        o4[lane * 4 + k] = t;
    }
}

extern "C" void kernel_launch(void* const* d_in, const int* in_sizes, int n_in,
                              void* d_out, int out_size, void* d_ws, size_t ws_size,
                              hipStream_t stream) {
    const float* dh    = (const float*)d_in[0];   // decoder_h [B,D]
    const float* key   = (const float*)d_in[1];   // key [B,L,A]
    // d_in[2] encoder_outputs — unused by the reference
    const float* prev  = (const float*)d_in[3];   // prev_att [B,L]
    const float* noise = (const float*)d_in[4];   // noise [B,L]
    const float* mask  = (const float*)d_in[5];   // mask [B,L]
    const float* W     = (const float*)d_in[6];   // W [A,D]
    const float* bias  = (const float*)d_in[7];   // b [A]
    const float* vw    = (const float*)d_in[8];   // v_weight [1,A]
    const float* vg    = (const float*)d_in[9];   // v_g [1]
    const float* vb    = (const float*)d_in[10];  // v_bias [1]
    const float* r     = (const float*)d_in[11];  // r [1]
    float* out = (float*)d_out;

    float* ws   = (float*)d_ws;
    float* vv2  = ws;                        // 512 floats
    float* scal = ws + Aa;                   // 1 float (padded to 1024)
    float* qb   = ws + 1024;                 // 64*512
    float* p    = ws + 1024 + Bb * Aa;       // 64*1024

    k_qb<<<dim3(4, Bb), 256, 0, stream>>>(dh, W, bias, vw, vg, vb, r, qb, vv2, scal);
    k_energy<<<dim3(Ll / 32, Bb), 256, 0, stream>>>(key, noise, mask, qb, vv2, scal, p);
    k_scan<<<Bb, 64, 0, stream>>>(p, prev, out);
}